// Round 6
// baseline (1985.827 us; speedup 1.0000x reference)
//
#include <hip/hip_runtime.h>
#include <hip/hip_bf16.h>
#include <math.h>

typedef float f32x4 __attribute__((ext_vector_type(4)));
typedef __bf16 bf16x8 __attribute__((ext_vector_type(8)));
typedef unsigned short u16x4 __attribute__((ext_vector_type(4)));

union U64 { unsigned long long u; u16x4 v; };
union U128 { unsigned long long q[2]; bf16x8 b; };

__device__ __forceinline__ unsigned short f2b(float x){ return __builtin_bit_cast(unsigned short, (__bf16)x); }

// ---- LDS: only K and V^T, per-head, double-buffered. 2 x 8KB = 16KB ----
// K  [64 tok][32 kch] bf16, 2 toks per 128B row, XOR swizzle kept inside 64B slot
__device__ __forceinline__ int koff(int b,int tok,int byt){
  return b*8192 + (tok>>1)*128 + (tok&1)*64 + (byt ^ (((tok>>1)&3)<<4));
}
// VT [32 vch][64 tok] bf16, stride 128B, XOR((row&7)<<4)
__device__ __forceinline__ int vtoff(int b,int vch,int byt){
  return b*8192 + 4096 + vch*128 + (byt ^ ((vch&7)<<4));
}
#define SMEM 16384

// pair-shuffle: build A/B fragment (8 contig k at k=8*lg, col=l16) from two D-tiles
// (lane(lg',l16) holds rows 4lg'+r of a 16-row tile, packed u64)
__device__ __forceinline__ bf16x8 frag32(unsigned long long t0, unsigned long long t1,
                                         int lg, int l16){
  const int sA = ((lg&1)<<5) + l16;
  unsigned long long a0=__shfl(t0,sA), b0=__shfl(t0,sA+16);
  unsigned long long a1=__shfl(t1,sA), b1=__shfl(t1,sA+16);
  U128 u; u.q[0]=(lg<2)?a0:a1; u.q[1]=(lg<2)?b0:b1;
  return u.b;
}
__device__ __forceinline__ unsigned long long pack4(f32x4 a){
  U64 u;
  #pragma unroll
  for(int r=0;r<4;++r) u.v[r]=f2b(a[r]);
  return u.u;
}

// Transpose + cast weights to bf16 [N][K]
__global__ void prep_weights(const float* __restrict__ wqkv, const float* __restrict__ wproj,
                             const float* __restrict__ wmlp1, const float* __restrict__ wmlp2,
                             unsigned short* __restrict__ ws){
  int idx = blockIdx.x*256 + threadIdx.x;
  if (idx < 110592){ int n=idx/192, k=idx%192; ws[idx] = f2b(wqkv[k*576+n]); }
  else if (idx < 147456){ int i=idx-110592; int n=i/192, k=i%192; ws[idx] = f2b(wproj[k*192+n]); }
  else if (idx < 294912){ int i=idx-147456; int n=i/192, k=i%192; ws[idx] = f2b(wmlp1[k*768+n]); }
  else if (idx < 442368){ int i=idx-294912; int n=i/768, k=i%768; ws[idx] = f2b(wmlp2[k*192+n]); }
}

// xw layout: [win][chgrp 48][tok 64][4]  (float idx = win*12288 + g*256 + tok*4 + e)
// K1: x[B,C,H,W] -> xw
__global__ void relayout_in(const float* __restrict__ x, float* __restrict__ xw){
  const int w = threadIdx.x, bh = blockIdx.x, b = bh>>8, h = bh&255;
  const int win = b*1024 + (h>>3)*32 + (w>>3);
  const int tok = (h&7)*8 + (w&7);
  const size_t src = (size_t)b*192*65536 + (size_t)h*256 + w;
  float* dst = xw + (size_t)win*12288 + tok*4;
  #pragma unroll 1
  for(int c0=0;c0<192;c0+=32){
    float buf[32];
    #pragma unroll
    for(int j=0;j<32;++j) buf[j] = x[src + (size_t)(c0+j)*65536];
    #pragma unroll
    for(int j4=0;j4<8;++j4)
      *(f32x4*)(dst + (c0/4+j4)*256) = (f32x4){buf[j4*4],buf[j4*4+1],buf[j4*4+2],buf[j4*4+3]};
  }
}

// K3: xw -> out[B,C,H,W]
__global__ void relayout_out(const float* __restrict__ rw, float* __restrict__ out){
  const int w = threadIdx.x, bh = blockIdx.x, b = bh>>8, h = bh&255;
  const int win = b*1024 + (h>>3)*32 + (w>>3);
  const int tok = (h&7)*8 + (w&7);
  const float* src = rw + (size_t)win*12288 + tok*4;
  const size_t dst = (size_t)b*192*65536 + (size_t)h*256 + w;
  #pragma unroll 1
  for(int c0=0;c0<192;c0+=32){
    f32x4 buf[8];
    #pragma unroll
    for(int j4=0;j4<8;++j4) buf[j4] = *(const f32x4*)(src + (c0/4+j4)*256);
    #pragma unroll
    for(int j=0;j<32;++j) out[dst + (size_t)(c0+j)*65536] = buf[j>>2][j&3];
  }
}

// K2: thread(w,lg,l16) owns tok=16w+l16, chs {16mt+4lg+r}. LDS = K/VT dbuf only.
template<int DIRECT>
__global__ void __launch_bounds__(256, 4) winblock(
    const float* xin, float* outp,
    const float* __restrict__ bqkv, const float* __restrict__ bproj,
    const float* __restrict__ ln1g, const float* __restrict__ ln1b,
    const float* __restrict__ ln2g, const float* __restrict__ ln2b,
    const float* __restrict__ bmlp1, const float* __restrict__ bmlp2,
    const unsigned short* __restrict__ wqkvT, const unsigned short* __restrict__ wprojT,
    const unsigned short* __restrict__ wmlp1T, const unsigned short* __restrict__ wmlp2T)
{
  __shared__ __align__(16) char sm[SMEM];
  const int tid=threadIdx.x, w=tid>>6, lg=(tid>>4)&3, l16=tid&15;
  const int wid=blockIdx.x;
  const int tok = 16*w + l16;

  // ---- load residual t[12]: ch=16mt+4lg+r, own tok ----
  f32x4 t[12];
  if(DIRECT){
    const int bb=wid>>10, wh=(wid>>5)&31, wwi=wid&31;
    const size_t imgoff=(size_t)bb*192*65536 + (size_t)(wh*8)*256 + (size_t)(wwi*8);
    const int tp=(tok>>3)*256+(tok&7);
    #pragma unroll
    for(int mt=0;mt<12;++mt)
      #pragma unroll
      for(int r=0;r<4;++r)
        t[mt][r]=xin[imgoff+(size_t)(16*mt+4*lg+r)*65536+tp];
  } else {
    const float* base = xin + (size_t)wid*12288 + tok*4;
    #pragma unroll
    for(int mt=0;mt<12;++mt) t[mt]=*(const f32x4*)(base + (4*mt+lg)*256);
  }

  bf16x8 hfr[6];   // h as ready-to-use MFMA fragments (k = 32*ks .. +31, col = own tok)

  // ---- register-only LayerNorm -> hfr ----
  auto layernorm=[&](const float* gg,const float* bbv){
    float s=0.f,s2=0.f;
    #pragma unroll
    for(int mt=0;mt<12;++mt){
      #pragma unroll
      for(int r=0;r<4;++r){ s+=t[mt][r]; s2+=t[mt][r]*t[mt][r]; }
    }
    s+=__shfl_xor(s,16); s+=__shfl_xor(s,32);
    s2+=__shfl_xor(s2,16); s2+=__shfl_xor(s2,32);
    const float mean=s*(1.f/192.f);
    const float rstd=rsqrtf(s2*(1.f/192.f)-mean*mean+1e-5f);
    unsigned long long hp_[12];
    #pragma unroll
    for(int mt=0;mt<12;++mt){
      const f32x4 g4=*(const f32x4*)(gg+16*mt+4*lg);
      const f32x4 b4=*(const f32x4*)(bbv+16*mt+4*lg);
      f32x4 hv;
      #pragma unroll
      for(int r=0;r<4;++r) hv[r]=(t[mt][r]-mean)*rstd*g4[r]+b4[r];
      hp_[mt]=pack4(hv);
    }
    #pragma unroll
    for(int ks=0;ks<6;++ks) hfr[ks]=frag32(hp_[2*ks],hp_[2*ks+1],lg,l16);
  };

  layernorm(ln1g, ln1b);

  // ---- produce QKV for head hh into LDS buf bsel; Q stays in regs (q0,q1) ----
  auto produce=[&](int hh,int bsel,unsigned long long& q0,unsigned long long& q1){
    f32x4 qa0={0,0,0,0},qa1={0,0,0,0},ka0={0,0,0,0},ka1={0,0,0,0},va0={0,0,0,0},va1={0,0,0,0};
    #pragma unroll
    for(int ks=0;ks<6;++ks){
      const bf16x8 hb=hfr[ks];
      const int ko=ks*32+lg*8;
      qa0=__builtin_amdgcn_mfma_f32_16x16x32_bf16(*(const bf16x8*)(wqkvT+(      hh*32   +l16)*192+ko),hb,qa0,0,0,0);
      qa1=__builtin_amdgcn_mfma_f32_16x16x32_bf16(*(const bf16x8*)(wqkvT+(      hh*32+16+l16)*192+ko),hb,qa1,0,0,0);
      ka0=__builtin_amdgcn_mfma_f32_16x16x32_bf16(*(const bf16x8*)(wqkvT+(192 + hh*32   +l16)*192+ko),hb,ka0,0,0,0);
      ka1=__builtin_amdgcn_mfma_f32_16x16x32_bf16(*(const bf16x8*)(wqkvT+(192 + hh*32+16+l16)*192+ko),hb,ka1,0,0,0);
      va0=__builtin_amdgcn_mfma_f32_16x16x32_bf16(hb,*(const bf16x8*)(wqkvT+(384 + hh*32   +l16)*192+ko),va0,0,0,0);
      va1=__builtin_amdgcn_mfma_f32_16x16x32_bf16(hb,*(const bf16x8*)(wqkvT+(384 + hh*32+16+l16)*192+ko),va1,0,0,0);
    }
    // Q: D[qch][own tok] -> pack (bias added)
    {
      const f32x4 b0=*(const f32x4*)(bqkv+hh*32   +4*lg);
      const f32x4 b1=*(const f32x4*)(bqkv+hh*32+16+4*lg);
      q0=pack4(qa0+b0); q1=pack4(qa1+b1);
    }
    // K: D[kch][own tok] -> K[tok][kch] (4 contig kch per thread)
    {
      const f32x4 b0=*(const f32x4*)(bqkv+192+hh*32   +4*lg);
      const f32x4 b1=*(const f32x4*)(bqkv+192+hh*32+16+4*lg);
      U64 u0,u1;
      #pragma unroll
      for(int r=0;r<4;++r){ u0.v[r]=f2b(ka0[r]+b0[r]); u1.v[r]=f2b(ka1[r]+b1[r]); }
      *(u16x4*)(sm+koff(bsel,tok, 8*lg   ))=u0.v;
      *(u16x4*)(sm+koff(bsel,tok, 8*lg+32))=u1.v;
    }
    // V: D[own tok-row 4lg+r][vch 16vt+l16] -> VT[vch][tok] (4 contig toks)
    {
      const float b0=bqkv[384+hh*32   +l16];
      const float b1=bqkv[384+hh*32+16+l16];
      U64 u0,u1;
      #pragma unroll
      for(int r=0;r<4;++r){ u0.v[r]=f2b(va0[r]+b0); u1.v[r]=f2b(va1[r]+b1); }
      *(u16x4*)(sm+vtoff(bsel,   l16,(16*w+4*lg)*2))=u0.v;
      *(u16x4*)(sm+vtoff(bsel,16+l16,(16*w+4*lg)*2))=u1.v;
    }
  };

  // ---- consume head hh from buf bsel: S -> softmax -> PV -> proj (into t) ----
  const float SM_C = 0.25503487f;  // log2(e)/sqrt(32)
  auto consume=[&](int hh,int bsel,unsigned long long q0,unsigned long long q1){
    const bf16x8 qf=frag32(q0,q1,lg,l16);
    f32x4 sv[4];
    #pragma unroll
    for(int kt=0;kt<4;++kt){
      const bf16x8 ak=*(const bf16x8*)(sm+koff(bsel,16*kt+l16,lg*16));
      sv[kt]=__builtin_amdgcn_mfma_f32_16x16x32_bf16(ak,qf,(f32x4){0,0,0,0},0,0,0);
    }
    float mx=-3.0e38f;
    #pragma unroll
    for(int kt=0;kt<4;++kt){
      #pragma unroll
      for(int r=0;r<4;++r) mx=fmaxf(mx,sv[kt][r]);
    }
    mx=fmaxf(mx,__shfl_xor(mx,16)); mx=fmaxf(mx,__shfl_xor(mx,32));
    float sum=0.f;
    #pragma unroll
    for(int kt=0;kt<4;++kt){
      #pragma unroll
      for(int r=0;r<4;++r){ float e=exp2f((sv[kt][r]-mx)*SM_C); sv[kt][r]=e; sum+=e; }
    }
    sum+=__shfl_xor(sum,16); sum+=__shfl_xor(sum,32);
    const float rs=1.f/sum;
    unsigned long long p64[4];
    #pragma unroll
    for(int kt=0;kt<4;++kt) p64[kt]=pack4(sv[kt]*rs);
    const bf16x8 pf0=frag32(p64[0],p64[1],lg,l16);
    const bf16x8 pf1=frag32(p64[2],p64[3],lg,l16);
    f32x4 ov0={0,0,0,0},ov1={0,0,0,0};
    {
      const bf16x8 a00=*(const bf16x8*)(sm+vtoff(bsel,   l16,   lg*16));
      const bf16x8 a01=*(const bf16x8*)(sm+vtoff(bsel,   l16,64+lg*16));
      const bf16x8 a10=*(const bf16x8*)(sm+vtoff(bsel,16+l16,   lg*16));
      const bf16x8 a11=*(const bf16x8*)(sm+vtoff(bsel,16+l16,64+lg*16));
      ov0=__builtin_amdgcn_mfma_f32_16x16x32_bf16(a00,pf0,ov0,0,0,0);
      ov0=__builtin_amdgcn_mfma_f32_16x16x32_bf16(a01,pf1,ov0,0,0,0);
      ov1=__builtin_amdgcn_mfma_f32_16x16x32_bf16(a10,pf0,ov1,0,0,0);
      ov1=__builtin_amdgcn_mfma_f32_16x16x32_bf16(a11,pf1,ov1,0,0,0);
    }
    const bf16x8 of=frag32(pack4(ov0),pack4(ov1),lg,l16);
    #pragma unroll
    for(int mt=0;mt<12;++mt){
      const bf16x8 aw=*(const bf16x8*)(wprojT+(16*mt+l16)*192+hh*32+lg*8);
      t[mt]=__builtin_amdgcn_mfma_f32_16x16x32_bf16(aw,of,t[mt],0,0,0);
    }
  };

  unsigned long long qA0,qA1,qB0,qB1;
  produce(0,0,qA0,qA1);
  __syncthreads();
  #pragma unroll 1
  for(int hp=0;hp<3;++hp){
    consume(2*hp, 0, qA0,qA1);
    produce(2*hp+1, 1, qB0,qB1);
    __syncthreads();
    consume(2*hp+1, 1, qB0,qB1);
    if(hp<2){ produce(2*hp+2, 0, qA0,qA1); }
    __syncthreads();
  }

  // ---- proj bias; LN2 -> hfr ----
  #pragma unroll
  for(int mt=0;mt<12;++mt) t[mt]+=*(const f32x4*)(bproj+16*mt+4*lg);
  layernorm(ln2g, ln2b);

  // ---- MLP: 24 chunks of 32 mch, fully register/shuffle, zero barriers ----
  #pragma unroll 1
  for(int c=0;c<24;++c){
    f32x4 d0={0,0,0,0},d1={0,0,0,0};
    #pragma unroll
    for(int ks=0;ks<6;++ks){
      const int ko=ks*32+lg*8;
      d0=__builtin_amdgcn_mfma_f32_16x16x32_bf16(*(const bf16x8*)(wmlp1T+(c*32   +l16)*192+ko),hfr[ks],d0,0,0,0);
      d1=__builtin_amdgcn_mfma_f32_16x16x32_bf16(*(const bf16x8*)(wmlp1T+(c*32+16+l16)*192+ko),hfr[ks],d1,0,0,0);
    }
    const f32x4 b10=*(const f32x4*)(bmlp1+c*32   +4*lg);
    const f32x4 b11=*(const f32x4*)(bmlp1+c*32+16+4*lg);
    f32x4 g0,g1;
    #pragma unroll
    for(int r=0;r<4;++r){
      float x0=d0[r]+b10[r], x1=d1[r]+b11[r];
      g0[r]=0.5f*x0*(1.f+erff(x0*0.70710678118654752f));
      g1[r]=0.5f*x1*(1.f+erff(x1*0.70710678118654752f));
    }
    const bf16x8 gf=frag32(pack4(g0),pack4(g1),lg,l16);
    #pragma unroll
    for(int mt=0;mt<12;++mt){
      const bf16x8 aw=*(const bf16x8*)(wmlp2T+(16*mt+l16)*768+c*32+lg*8);
      t[mt]=__builtin_amdgcn_mfma_f32_16x16x32_bf16(aw,gf,t[mt],0,0,0);
    }
  }

  // ---- epilogue: out = t + bmlp2 ----
  if(DIRECT){
    const int bb=wid>>10, wh=(wid>>5)&31, wwi=wid&31;
    const size_t imgoff=(size_t)bb*192*65536 + (size_t)(wh*8)*256 + (size_t)(wwi*8);
    const int tp=(tok>>3)*256+(tok&7);
    #pragma unroll
    for(int mt=0;mt<12;++mt){
      const f32x4 b2=*(const f32x4*)(bmlp2+16*mt+4*lg);
      #pragma unroll
      for(int r=0;r<4;++r)
        outp[imgoff+(size_t)(16*mt+4*lg+r)*65536+tp]=t[mt][r]+b2[r];
    }
  } else {
    float* base = outp + (size_t)wid*12288 + tok*4;
    #pragma unroll
    for(int mt=0;mt<12;++mt){
      const f32x4 b2=*(const f32x4*)(bmlp2+16*mt+4*lg);
      *(f32x4*)(base + (4*mt+lg)*256)=t[mt]+b2;
    }
  }
}

extern "C" void kernel_launch(void* const* d_in, const int* in_sizes, int n_in,
                              void* d_out, int out_size, void* d_ws, size_t ws_size,
                              hipStream_t stream) {
  const float* x      = (const float*)d_in[0];
  const float* w_qkv  = (const float*)d_in[1];
  const float* b_qkv  = (const float*)d_in[2];
  const float* w_proj = (const float*)d_in[3];
  const float* b_proj = (const float*)d_in[4];
  const float* ln1g   = (const float*)d_in[5];
  const float* ln1b   = (const float*)d_in[6];
  const float* ln2g   = (const float*)d_in[7];
  const float* ln2b   = (const float*)d_in[8];
  const float* w_mlp1 = (const float*)d_in[9];
  const float* b_mlp1 = (const float*)d_in[10];
  const float* w_mlp2 = (const float*)d_in[11];
  const float* b_mlp2 = (const float*)d_in[12];
  unsigned short* wsu = (unsigned short*)d_ws;
  float* out = (float*)d_out;

  prep_weights<<<dim3(1728), dim3(256), 0, stream>>>(w_qkv, w_proj, w_mlp1, w_mlp2, wsu);

  const size_t need = (size_t)(1<<20) + 201326592ull;   // weights pad + xw
  if (ws_size >= need){
    float* xw = (float*)((char*)d_ws + (1<<20));
    relayout_in<<<dim3(1024), dim3(256), 0, stream>>>(x, xw);
    winblock<0><<<dim3(4096), dim3(256), 0, stream>>>(
        xw, xw, b_qkv, b_proj, ln1g, ln1b, ln2g, ln2b, b_mlp1, b_mlp2,
        wsu, wsu+110592, wsu+147456, wsu+294912);
    relayout_out<<<dim3(1024), dim3(256), 0, stream>>>(xw, out);
  } else {
    winblock<1><<<dim3(4096), dim3(256), 0, stream>>>(
        x, out, b_qkv, b_proj, ln1g, ln1b, ln2g, ln2b, b_mlp1, b_mlp2,
        wsu, wsu+110592, wsu+147456, wsu+294912);
  }
}

// Round 7
// 896.391 us; speedup vs baseline: 2.2154x; 2.2154x over previous
//
#include <hip/hip_runtime.h>
#include <hip/hip_bf16.h>
#include <math.h>

typedef float f32x4 __attribute__((ext_vector_type(4)));
typedef float f32x2 __attribute__((ext_vector_type(2)));
typedef __bf16 bf16x8 __attribute__((ext_vector_type(8)));
typedef unsigned short u16x4 __attribute__((ext_vector_type(4)));

// ---------------- LDS map (40960 B exactly -> 4 blocks/CU) ----------------
// SA  [64 tok][192 ch] bf16, stride 384, XOR((row&7)<<4)           : 24576
// RQ/RK/RO: tok-paired [32 rows][128 B] (2 toks/row)               : 3 x 4096
// RVT [32 d][64 tok] bf16, stride 128, XOR((row&7)<<4)             : 4096
// G (MLP, overlays RQ..RO+RVT) [64 tok][128 mch] bf16, stride 256  : 16384
// red (LN, overlays RQ)                                            : 2048
#define SA_B  0
#define RQ_B  24576
#define RK_B  28672
#define RVT_B 32768
#define RO_B  36864
#define RG_B  24576
#define SMEM  40960

__device__ __forceinline__ int sa_off(int row,int byte){ return SA_B + row*384 + (byte ^ ((row&7)<<4)); }
__device__ __forceinline__ int vt_off(int row,int byte){ return RVT_B+ row*128 + (byte ^ ((row&7)<<4)); }
__device__ __forceinline__ int g_off (int row,int byte){ return RG_B + row*256 + (byte ^ ((row&7)<<4)); }
// tok-paired: 2 toks per 128B row; XOR stays inside the 64B slot (&3 mask — bugfix vs R5)
__device__ __forceinline__ int qp_off(int base,int tok,int byte){
  return base + (tok>>1)*128 + (tok&1)*64 + (byte ^ (((tok>>1)&3)<<4));
}
__device__ __forceinline__ unsigned short f2b(float x){ return __builtin_bit_cast(unsigned short, (__bf16)x); }

union U64 { unsigned long long u; u16x4 v; };
union U128 { unsigned long long q[2]; bf16x8 b; };

// Transpose + cast weights to bf16 [N][K]
__global__ void prep_weights(const float* __restrict__ wqkv, const float* __restrict__ wproj,
                             const float* __restrict__ wmlp1, const float* __restrict__ wmlp2,
                             unsigned short* __restrict__ ws){
  int idx = blockIdx.x*256 + threadIdx.x;
  if (idx < 110592){ int n=idx/192, k=idx%192; ws[idx] = f2b(wqkv[k*576+n]); }
  else if (idx < 147456){ int i=idx-110592; int n=i/192, k=i%192; ws[idx] = f2b(wproj[k*192+n]); }
  else if (idx < 294912){ int i=idx-147456; int n=i/192, k=i%192; ws[idx] = f2b(wmlp1[k*768+n]); }
  else if (idx < 442368){ int i=idx-294912; int n=i/768, k=i%768; ws[idx] = f2b(wmlp2[k*192+n]); }
}

// xw layout: [win][chgrp 48][tok 64][4]  (float idx = win*12288 + g*256 + tok*4 + e)
// K1: x[B,C,H,W] -> xw (both sides coalesced; writes are full 128B lines)
__global__ void relayout_in(const float* __restrict__ x, float* __restrict__ xw){
  const int w = threadIdx.x, bh = blockIdx.x, b = bh>>8, h = bh&255;
  const int win = b*1024 + (h>>3)*32 + (w>>3);
  const int tok = (h&7)*8 + (w&7);
  const size_t src = (size_t)b*192*65536 + (size_t)h*256 + w;
  float* dst = xw + (size_t)win*12288 + tok*4;
  #pragma unroll 1
  for(int c0=0;c0<192;c0+=32){
    float buf[32];
    #pragma unroll
    for(int j=0;j<32;++j) buf[j] = x[src + (size_t)(c0+j)*65536];
    #pragma unroll
    for(int j4=0;j4<8;++j4)
      *(f32x4*)(dst + (c0/4+j4)*256) = (f32x4){buf[j4*4],buf[j4*4+1],buf[j4*4+2],buf[j4*4+3]};
  }
}

// K3: xw -> out[B,C,H,W]
__global__ void relayout_out(const float* __restrict__ rw, float* __restrict__ out){
  const int w = threadIdx.x, bh = blockIdx.x, b = bh>>8, h = bh&255;
  const int win = b*1024 + (h>>3)*32 + (w>>3);
  const int tok = (h&7)*8 + (w&7);
  const float* src = rw + (size_t)win*12288 + tok*4;
  const size_t dst = (size_t)b*192*65536 + (size_t)h*256 + w;
  #pragma unroll 1
  for(int c0=0;c0<192;c0+=32){
    f32x4 buf[8];
    #pragma unroll
    for(int j4=0;j4<8;++j4) buf[j4] = *(const f32x4*)(src + (c0/4+j4)*256);
    #pragma unroll
    for(int j=0;j<32;++j) out[dst + (size_t)(c0+j)*65536] = buf[j>>2][j&3];
  }
}

// K2. Thread (w,lg,l16): owns toks {16tt+l16} x chs {48w+16mt+4lg+r}. 40KB LDS.
template<int DIRECT>
__global__ void __launch_bounds__(256, 4) winblock(
    const float* xin, float* outp,
    const float* __restrict__ bqkv, const float* __restrict__ bproj,
    const float* __restrict__ ln1g, const float* __restrict__ ln1b,
    const float* __restrict__ ln2g, const float* __restrict__ ln2b,
    const float* __restrict__ bmlp1, const float* __restrict__ bmlp2,
    const unsigned short* __restrict__ wqkvT, const unsigned short* __restrict__ wprojT,
    const unsigned short* __restrict__ wmlp1T, const unsigned short* __restrict__ wmlp2T)
{
  __shared__ __align__(16) char sm[SMEM];
  const int tid=threadIdx.x, w=tid>>6, lg=(tid>>4)&3, l16=tid&15;
  const int wid=blockIdx.x;
  f32x2* red = (f32x2*)(sm + RQ_B);

  // ---- residual t[mt][tt]: ch 48w+16mt+4lg+r, tok 16tt+l16 ----
  f32x4 t[3][4];
  if(DIRECT){
    const int bb=wid>>10, wh=(wid>>5)&31, wwi=wid&31;
    const size_t imgoff=(size_t)bb*192*65536 + (size_t)(wh*8)*256 + (size_t)(wwi*8);
    #pragma unroll
    for(int mt=0;mt<3;++mt)
      #pragma unroll
      for(int tt=0;tt<4;++tt){
        const int T=16*tt+l16, tp=(T>>3)*256+(T&7);
        #pragma unroll
        for(int r=0;r<4;++r)
          t[mt][tt][r]=xin[imgoff+(size_t)(48*w+16*mt+4*lg+r)*65536+tp];
      }
  } else {
    const float* base = xin + (size_t)wid*12288;
    #pragma unroll
    for(int mt=0;mt<3;++mt)
      #pragma unroll
      for(int tt=0;tt<4;++tt)
        t[mt][tt]=*(const f32x4*)(base + (12*w+4*mt+lg)*256 + (16*tt+l16)*4);
  }

  // ---- LayerNorm -> bf16 into SA (contains one internal barrier) ----
  auto layernorm = [&](const float* gg, const float* bbv){
    float s[4], s2[4];
    #pragma unroll
    for(int tt=0;tt<4;++tt){
      float a=0.f,b2=0.f;
      #pragma unroll
      for(int mt=0;mt<3;++mt){
        #pragma unroll
        for(int r=0;r<4;++r){ a+=t[mt][tt][r]; b2+=t[mt][tt][r]*t[mt][tt][r]; }
      }
      a+=__shfl_xor(a,16); a+=__shfl_xor(a,32);
      b2+=__shfl_xor(b2,16); b2+=__shfl_xor(b2,32);
      s[tt]=a; s2[tt]=b2;
    }
    if(lg==0) red[w*64 +  0+l16]=(f32x2){s[0],s2[0]};
    if(lg==1) red[w*64 + 16+l16]=(f32x2){s[1],s2[1]};
    if(lg==2) red[w*64 + 32+l16]=(f32x2){s[2],s2[2]};
    if(lg==3) red[w*64 + 48+l16]=(f32x2){s[3],s2[3]};
    __syncthreads();
    float mean[4], rstd[4];
    #pragma unroll
    for(int tt=0;tt<4;++tt){
      float S=0.f,S2=0.f;
      #pragma unroll
      for(int w2=0;w2<4;++w2){ f32x2 v=red[w2*64+16*tt+l16]; S+=v.x; S2+=v.y; }
      mean[tt]=S*(1.f/192.f);
      rstd[tt]=rsqrtf(S2*(1.f/192.f)-mean[tt]*mean[tt]+1e-5f);
    }
    #pragma unroll
    for(int mt=0;mt<3;++mt){
      const f32x4 g4=*(const f32x4*)(gg+48*w+16*mt+4*lg);
      const f32x4 b4=*(const f32x4*)(bbv+48*w+16*mt+4*lg);
      #pragma unroll
      for(int tt=0;tt<4;++tt){
        u16x4 pk;
        #pragma unroll
        for(int r=0;r<4;++r) pk[r]=f2b((t[mt][tt][r]-mean[tt])*rstd[tt]*g4[r]+b4[r]);
        *(u16x4*)(sm+sa_off(16*tt+l16,(48*w+16*mt+4*lg)*2))=pk;
      }
    }
  };

  layernorm(ln1g, ln1b);
  __syncthreads();   // h visible

  // ---- QKV producer: wave w -> ct=w>>1 (ch-half of head), tok-tiles {2(w&1),+1} ----
  const int ct=w>>1, tbase=2*(w&1);
  auto c1=[&](int hh){
    f32x4 qa[2],ka[2],va[2];
    #pragma unroll
    for(int i=0;i<2;++i){ qa[i]=(f32x4){0,0,0,0}; ka[i]=(f32x4){0,0,0,0}; va[i]=(f32x4){0,0,0,0}; }
    #pragma unroll
    for(int ks=0;ks<6;++ks){
      bf16x8 hfrag[2];
      #pragma unroll
      for(int i=0;i<2;++i) hfrag[i]=*(const bf16x8*)(sm+sa_off(16*(tbase+i)+l16, ks*64+lg*16));
      const bf16x8 awq=*(const bf16x8*)(wqkvT+(      hh*32+ct*16+l16)*192+ks*32+lg*8);
      const bf16x8 awk=*(const bf16x8*)(wqkvT+(192 + hh*32+ct*16+l16)*192+ks*32+lg*8);
      const bf16x8 bwv=*(const bf16x8*)(wqkvT+(384 + hh*32+ct*16+l16)*192+ks*32+lg*8);
      #pragma unroll
      for(int i=0;i<2;++i){
        qa[i]=__builtin_amdgcn_mfma_f32_16x16x32_bf16(awq,hfrag[i],qa[i],0,0,0);  // D[qch][tok]
        ka[i]=__builtin_amdgcn_mfma_f32_16x16x32_bf16(awk,hfrag[i],ka[i],0,0,0);
        va[i]=__builtin_amdgcn_mfma_f32_16x16x32_bf16(hfrag[i],bwv,va[i],0,0,0);  // D[tok][vch]
      }
    }
    const f32x4 bq4=*(const f32x4*)(bqkv+      hh*32+ct*16+4*lg);
    const f32x4 bk4=*(const f32x4*)(bqkv+192 + hh*32+ct*16+4*lg);
    const float bv =bqkv[384 + hh*32+ct*16+l16];
    #pragma unroll
    for(int i=0;i<2;++i){
      const int tok=16*(tbase+i)+l16;
      u16x4 pq,pk,pv;
      #pragma unroll
      for(int r=0;r<4;++r){
        pq[r]=f2b(qa[i][r]+bq4[r]);
        pk[r]=f2b(ka[i][r]+bk4[r]);
        pv[r]=f2b(va[i][r]+bv);
      }
      *(u16x4*)(sm+qp_off(RQ_B,tok,32*ct+8*lg))=pq;                  // Q[tok][qch]
      *(u16x4*)(sm+qp_off(RK_B,tok,32*ct+8*lg))=pk;                  // K[tok][qch]
      *(u16x4*)(sm+vt_off(ct*16+l16,(16*(tbase+i)+4*lg)*2))=pv;      // VT[vch][tok]
    }
  };

  c1(0);
  __syncthreads();

  const float SM_C = 0.25503487f;  // log2(e)/sqrt(32), applied in f32 at exp2
  #pragma unroll 1
  for(int h=0;h<6;++h){
    // ---- S^T = K.Q (A=K rows=ktok, B=Q col=own q) ; softmax in-register ----
    {
      const int q=16*w+l16;
      const bf16x8 bqf=*(const bf16x8*)(sm+qp_off(RQ_B,q,lg*16));
      f32x4 sv[4];
      #pragma unroll
      for(int kt=0;kt<4;++kt){
        const bf16x8 akf=*(const bf16x8*)(sm+qp_off(RK_B,16*kt+l16,lg*16));
        sv[kt]=__builtin_amdgcn_mfma_f32_16x16x32_bf16(akf,bqf,(f32x4){0,0,0,0},0,0,0);
      }
      float mx=-3.0e38f;
      #pragma unroll
      for(int kt=0;kt<4;++kt){
        #pragma unroll
        for(int r=0;r<4;++r) mx=fmaxf(mx,sv[kt][r]);
      }
      mx=fmaxf(mx,__shfl_xor(mx,16)); mx=fmaxf(mx,__shfl_xor(mx,32));
      float sum=0.f;
      #pragma unroll
      for(int kt=0;kt<4;++kt){
        #pragma unroll
        for(int r=0;r<4;++r){ float e=exp2f((sv[kt][r]-mx)*SM_C); sv[kt][r]=e; sum+=e; }
      }
      sum+=__shfl_xor(sum,16); sum+=__shfl_xor(sum,32);
      const float rs=1.f/sum;
      U64 pk0,pk1,pk2,pk3;
      #pragma unroll
      for(int r=0;r<4;++r){ pk0.v[r]=f2b(sv[0][r]*rs); pk1.v[r]=f2b(sv[1][r]*rs);
                            pk2.v[r]=f2b(sv[2][r]*rs); pk3.v[r]=f2b(sv[3][r]*rs); }
      // in-register P-fragment build: lane(lg,l16) needs ktok {8lg..8lg+7} (+32) for q=16w+l16
      const int srcA = ((lg&1)<<5) + l16, srcB = srcA + 16;
      unsigned long long rA0=__shfl(pk0.u,srcA), rB0=__shfl(pk0.u,srcB);
      unsigned long long rA1=__shfl(pk1.u,srcA), rB1=__shfl(pk1.u,srcB);
      unsigned long long rA2=__shfl(pk2.u,srcA), rB2=__shfl(pk2.u,srcB);
      unsigned long long rA3=__shfl(pk3.u,srcA), rB3=__shfl(pk3.u,srcB);
      U128 pf0, pf1;
      pf0.q[0]=(lg<2)?rA0:rA1;  pf0.q[1]=(lg<2)?rB0:rB1;   // ktok 0..31
      pf1.q[0]=(lg<2)?rA2:rA3;  pf1.q[1]=(lg<2)?rB2:rB3;   // ktok 32..63
      // ---- PV: A=VT (rows d), B=P (col=own q) -> D[d][q]; write O[q][d] ----
      f32x4 ov[2]={(f32x4){0,0,0,0},(f32x4){0,0,0,0}};
      #pragma unroll
      for(int dt=0;dt<2;++dt){
        const bf16x8 av0=*(const bf16x8*)(sm+vt_off(16*dt+l16,lg*16));
        const bf16x8 av1=*(const bf16x8*)(sm+vt_off(16*dt+l16,64+lg*16));
        ov[dt]=__builtin_amdgcn_mfma_f32_16x16x32_bf16(av0,pf0.b,ov[dt],0,0,0);
        ov[dt]=__builtin_amdgcn_mfma_f32_16x16x32_bf16(av1,pf1.b,ov[dt],0,0,0);
      }
      #pragma unroll
      for(int dt=0;dt<2;++dt){
        u16x4 po;
        #pragma unroll
        for(int r=0;r<4;++r) po[r]=f2b(ov[dt][r]);
        *(u16x4*)(sm+qp_off(RO_B,q,32*dt+8*lg))=po;   // own q row
      }
    }
    __syncthreads();   // O visible; Q/K/VT reads done
    // ---- proj accumulate directly into t: A=Wproj rows=own outch, B=O col=tok ----
    {
      bf16x8 bo[4];
      #pragma unroll
      for(int tt=0;tt<4;++tt) bo[tt]=*(const bf16x8*)(sm+qp_off(RO_B,16*tt+l16,lg*16));
      #pragma unroll
      for(int mt=0;mt<3;++mt){
        const bf16x8 aw=*(const bf16x8*)(wprojT+(16*(3*w+mt)+l16)*192+h*32+lg*8);
        #pragma unroll
        for(int tt=0;tt<4;++tt)
          t[mt][tt]=__builtin_amdgcn_mfma_f32_16x16x32_bf16(aw,bo[tt],t[mt][tt],0,0,0);
      }
    }
    if(h<5){ c1(h+1); __syncthreads(); }
  }

  // ---- proj bias once ----
  #pragma unroll
  for(int mt=0;mt<3;++mt){
    const f32x4 bp=*(const f32x4*)(bproj+48*w+16*mt+4*lg);
    #pragma unroll
    for(int tt=0;tt<4;++tt) t[mt][tt]+=bp;
  }

  // ---- LN2 (red overlays RQ; all Q reads finished) ----
  layernorm(ln2g, ln2b);
  __syncthreads();   // h2 visible; attn buffers dead -> G area free

  // ---- MLP: 6 chunks of 128 mch; MLP2 accumulates into t ----
  #pragma unroll 1
  for(int qc=0;qc<6;++qc){
    f32x4 g[2][4];
    #pragma unroll
    for(int m=0;m<2;++m)
      #pragma unroll
      for(int tt=0;tt<4;++tt) g[m][tt]=(f32x4){0,0,0,0};
    #pragma unroll
    for(int ks=0;ks<6;++ks){
      bf16x8 bh2[4];
      #pragma unroll
      for(int tt=0;tt<4;++tt) bh2[tt]=*(const bf16x8*)(sm+sa_off(16*tt+l16,ks*64+lg*16));
      #pragma unroll
      for(int m=0;m<2;++m){
        const bf16x8 aw=*(const bf16x8*)(wmlp1T+(qc*128+16*(2*w+m)+l16)*192+ks*32+lg*8);
        #pragma unroll
        for(int tt=0;tt<4;++tt)
          g[m][tt]=__builtin_amdgcn_mfma_f32_16x16x32_bf16(aw,bh2[tt],g[m][tt],0,0,0);
      }
    }
    #pragma unroll
    for(int m=0;m<2;++m){
      const f32x4 b1=*(const f32x4*)(bmlp1+qc*128+16*(2*w+m)+4*lg);
      #pragma unroll
      for(int tt=0;tt<4;++tt){
        u16x4 pg;
        #pragma unroll
        for(int r=0;r<4;++r){
          const float xv=g[m][tt][r]+b1[r];
          pg[r]=f2b(0.5f*xv*(1.f+erff(xv*0.70710678118654752f)));
        }
        *(u16x4*)(sm+g_off(16*tt+l16,(16*(2*w+m)+4*lg)*2))=pg;  // G[tok][mch]
      }
    }
    __syncthreads();   // G visible
    #pragma unroll
    for(int ks2=0;ks2<4;++ks2){
      bf16x8 bg[4];
      #pragma unroll
      for(int tt=0;tt<4;++tt) bg[tt]=*(const bf16x8*)(sm+g_off(16*tt+l16,ks2*64+lg*16));
      #pragma unroll
      for(int mt=0;mt<3;++mt){
        const bf16x8 aw2=*(const bf16x8*)(wmlp2T+(16*(3*w+mt)+l16)*768+qc*128+ks2*32+lg*8);
        #pragma unroll
        for(int tt=0;tt<4;++tt)
          t[mt][tt]=__builtin_amdgcn_mfma_f32_16x16x32_bf16(aw2,bg[tt],t[mt][tt],0,0,0);
      }
    }
    if(qc<5) __syncthreads();  // WAR before next G write
  }

  // ---- Final: out = t + bmlp2 ----
  if(DIRECT){
    const int bb=wid>>10, wh=(wid>>5)&31, wwi=wid&31;
    const size_t imgoff=(size_t)bb*192*65536 + (size_t)(wh*8)*256 + (size_t)(wwi*8);
    #pragma unroll
    for(int mt=0;mt<3;++mt){
      const f32x4 b2=*(const f32x4*)(bmlp2+48*w+16*mt+4*lg);
      #pragma unroll
      for(int tt=0;tt<4;++tt){
        const int T=16*tt+l16, tp=(T>>3)*256+(T&7);
        #pragma unroll
        for(int r=0;r<4;++r)
          outp[imgoff+(size_t)(48*w+16*mt+4*lg+r)*65536+tp]=t[mt][tt][r]+b2[r];
      }
    }
  } else {
    float* base = outp + (size_t)wid*12288;
    #pragma unroll
    for(int mt=0;mt<3;++mt){
      const f32x4 b2=*(const f32x4*)(bmlp2+48*w+16*mt+4*lg);
      #pragma unroll
      for(int tt=0;tt<4;++tt)
        *(f32x4*)(base + (12*w+4*mt+lg)*256 + (16*tt+l16)*4)=t[mt][tt]+b2;
    }
  }
}

extern "C" void kernel_launch(void* const* d_in, const int* in_sizes, int n_in,
                              void* d_out, int out_size, void* d_ws, size_t ws_size,
                              hipStream_t stream) {
  const float* x      = (const float*)d_in[0];
  const float* w_qkv  = (const float*)d_in[1];
  const float* b_qkv  = (const float*)d_in[2];
  const float* w_proj = (const float*)d_in[3];
  const float* b_proj = (const float*)d_in[4];
  const float* ln1g   = (const float*)d_in[5];
  const float* ln1b   = (const float*)d_in[6];
  const float* ln2g   = (const float*)d_in[7];
  const float* ln2b   = (const float*)d_in[8];
  const float* w_mlp1 = (const float*)d_in[9];
  const float* b_mlp1 = (const float*)d_in[10];
  const float* w_mlp2 = (const float*)d_in[11];
  const float* b_mlp2 = (const float*)d_in[12];
  unsigned short* wsu = (unsigned short*)d_ws;
  float* out = (float*)d_out;

  prep_weights<<<dim3(1728), dim3(256), 0, stream>>>(w_qkv, w_proj, w_mlp1, w_mlp2, wsu);

  const size_t need = (size_t)(1<<20) + 201326592ull;   // weights pad + xw
  if (ws_size >= need){
    float* xw = (float*)((char*)d_ws + (1<<20));
    relayout_in<<<dim3(1024), dim3(256), 0, stream>>>(x, xw);
    winblock<0><<<dim3(4096), dim3(256), 0, stream>>>(
        xw, xw, b_qkv, b_proj, ln1g, ln1b, ln2g, ln2b, b_mlp1, b_mlp2,
        wsu, wsu+110592, wsu+147456, wsu+294912);
    relayout_out<<<dim3(1024), dim3(256), 0, stream>>>(xw, out);
  } else {
    winblock<1><<<dim3(4096), dim3(256), 0, stream>>>(
        x, out, b_qkv, b_proj, ln1g, ln1b, ln2g, ln2b, b_mlp1, b_mlp2,
        wsu, wsu+110592, wsu+147456, wsu+294912);
  }
}

// Round 8
// 895.136 us; speedup vs baseline: 2.2185x; 1.0014x over previous
//
#include <hip/hip_runtime.h>
#include <hip/hip_bf16.h>
#include <math.h>

typedef float f32x4 __attribute__((ext_vector_type(4)));
typedef float f32x2 __attribute__((ext_vector_type(2)));
typedef __bf16 bf16x8 __attribute__((ext_vector_type(8)));
typedef unsigned short u16x4 __attribute__((ext_vector_type(4)));

// ---------------- LDS map (40960 B exactly -> 4 blocks/CU) ----------------
#define SA_B  0
#define RQ_B  24576
#define RK_B  28672
#define RVT_B 32768
#define RO_B  36864
#define RG_B  24576
#define SMEM  40960

__device__ __forceinline__ int sa_off(int row,int byte){ return SA_B + row*384 + (byte ^ ((row&7)<<4)); }
__device__ __forceinline__ int vt_off(int row,int byte){ return RVT_B+ row*128 + (byte ^ ((row&7)<<4)); }
__device__ __forceinline__ int g_off (int row,int byte){ return RG_B + row*256 + (byte ^ ((row&7)<<4)); }
__device__ __forceinline__ int qp_off(int base,int tok,int byte){
  return base + (tok>>1)*128 + (tok&1)*64 + (byte ^ (((tok>>1)&3)<<4));
}
__device__ __forceinline__ unsigned short f2b(float x){ return __builtin_bit_cast(unsigned short, (__bf16)x); }

union U64 { unsigned long long u; u16x4 v; };
union U128 { unsigned long long q[2]; bf16x8 b; };

// Transpose + cast weights to bf16 [N][K]
__global__ void prep_weights(const float* __restrict__ wqkv, const float* __restrict__ wproj,
                             const float* __restrict__ wmlp1, const float* __restrict__ wmlp2,
                             unsigned short* __restrict__ ws){
  int idx = blockIdx.x*256 + threadIdx.x;
  if (idx < 110592){ int n=idx/192, k=idx%192; ws[idx] = f2b(wqkv[k*576+n]); }
  else if (idx < 147456){ int i=idx-110592; int n=i/192, k=i%192; ws[idx] = f2b(wproj[k*192+n]); }
  else if (idx < 294912){ int i=idx-147456; int n=i/192, k=i%192; ws[idx] = f2b(wmlp1[k*768+n]); }
  else if (idx < 442368){ int i=idx-294912; int n=i/768, k=i%768; ws[idx] = f2b(wmlp2[k*192+n]); }
}

// xw layout: [win][chgrp 48][tok 64][4]  (float idx = win*12288 + g*256 + tok*4 + e)
// K1: x[B,C,H,W] -> xw (both sides coalesced; writes are full 128B lines)
__global__ void relayout_in(const float* __restrict__ x, float* __restrict__ xw){
  const int w = threadIdx.x, bh = blockIdx.x, b = bh>>8, h = bh&255;
  const int win = b*1024 + (h>>3)*32 + (w>>3);
  const int tok = (h&7)*8 + (w&7);
  const size_t src = (size_t)b*192*65536 + (size_t)h*256 + w;
  float* dst = xw + (size_t)win*12288 + tok*4;
  #pragma unroll 1
  for(int c0=0;c0<192;c0+=32){
    float buf[32];
    #pragma unroll
    for(int j=0;j<32;++j) buf[j] = x[src + (size_t)(c0+j)*65536];
    #pragma unroll
    for(int j4=0;j4<8;++j4)
      *(f32x4*)(dst + (c0/4+j4)*256) = (f32x4){buf[j4*4],buf[j4*4+1],buf[j4*4+2],buf[j4*4+3]};
  }
}

// K3: xw -> out[B,C,H,W]
__global__ void relayout_out(const float* __restrict__ rw, float* __restrict__ out){
  const int w = threadIdx.x, bh = blockIdx.x, b = bh>>8, h = bh&255;
  const int win = b*1024 + (h>>3)*32 + (w>>3);
  const int tok = (h&7)*8 + (w&7);
  const float* src = rw + (size_t)win*12288 + tok*4;
  const size_t dst = (size_t)b*192*65536 + (size_t)h*256 + w;
  #pragma unroll 1
  for(int c0=0;c0<192;c0+=32){
    f32x4 buf[8];
    #pragma unroll
    for(int j4=0;j4<8;++j4) buf[j4] = *(const f32x4*)(src + (c0/4+j4)*256);
    #pragma unroll
    for(int j=0;j<32;++j) out[dst + (size_t)(c0+j)*65536] = buf[j>>2][j&3];
  }
}

// K2. Thread (w,lg,l16): owns toks {16tt+l16} x chs {48w+16mt+4lg+r}. 40KB LDS.
template<int DIRECT>
__global__ void __launch_bounds__(256, 4) winblock(
    const float* xin, float* outp,
    const float* __restrict__ bqkv, const float* __restrict__ bproj,
    const float* __restrict__ ln1g, const float* __restrict__ ln1b,
    const float* __restrict__ ln2g, const float* __restrict__ ln2b,
    const float* __restrict__ bmlp1, const float* __restrict__ bmlp2,
    const unsigned short* __restrict__ wqkvT, const unsigned short* __restrict__ wprojT,
    const unsigned short* __restrict__ wmlp1T, const unsigned short* __restrict__ wmlp2T)
{
  __shared__ __align__(16) char sm[SMEM];
  const int tid=threadIdx.x, w=tid>>6, lg=(tid>>4)&3, l16=tid&15;
  const int wid=blockIdx.x;
  f32x2* red = (f32x2*)(sm + RQ_B);

  // ---- residual t[mt][tt]: ch 48w+16mt+4lg+r, tok 16tt+l16 ----
  f32x4 t[3][4];
  if(DIRECT){
    const int bb=wid>>10, wh=(wid>>5)&31, wwi=wid&31;
    const size_t imgoff=(size_t)bb*192*65536 + (size_t)(wh*8)*256 + (size_t)(wwi*8);
    #pragma unroll
    for(int mt=0;mt<3;++mt)
      #pragma unroll
      for(int tt=0;tt<4;++tt){
        const int T=16*tt+l16, tp=(T>>3)*256+(T&7);
        #pragma unroll
        for(int r=0;r<4;++r)
          t[mt][tt][r]=xin[imgoff+(size_t)(48*w+16*mt+4*lg+r)*65536+tp];
      }
  } else {
    const float* base = xin + (size_t)wid*12288;
    #pragma unroll
    for(int mt=0;mt<3;++mt)
      #pragma unroll
      for(int tt=0;tt<4;++tt)
        t[mt][tt]=*(const f32x4*)(base + (12*w+4*mt+lg)*256 + (16*tt+l16)*4);
  }

  // ---- LayerNorm -> bf16 into SA (contains one internal barrier) ----
  auto layernorm = [&](const float* gg, const float* bbv){
    float s[4], s2[4];
    #pragma unroll
    for(int tt=0;tt<4;++tt){
      float a=0.f,b2=0.f;
      #pragma unroll
      for(int mt=0;mt<3;++mt){
        #pragma unroll
        for(int r=0;r<4;++r){ a+=t[mt][tt][r]; b2+=t[mt][tt][r]*t[mt][tt][r]; }
      }
      a+=__shfl_xor(a,16); a+=__shfl_xor(a,32);
      b2+=__shfl_xor(b2,16); b2+=__shfl_xor(b2,32);
      s[tt]=a; s2[tt]=b2;
    }
    if(lg==0) red[w*64 +  0+l16]=(f32x2){s[0],s2[0]};
    if(lg==1) red[w*64 + 16+l16]=(f32x2){s[1],s2[1]};
    if(lg==2) red[w*64 + 32+l16]=(f32x2){s[2],s2[2]};
    if(lg==3) red[w*64 + 48+l16]=(f32x2){s[3],s2[3]};
    __syncthreads();
    float mean[4], rstd[4];
    #pragma unroll
    for(int tt=0;tt<4;++tt){
      float S=0.f,S2=0.f;
      #pragma unroll
      for(int w2=0;w2<4;++w2){ f32x2 v=red[w2*64+16*tt+l16]; S+=v.x; S2+=v.y; }
      mean[tt]=S*(1.f/192.f);
      rstd[tt]=rsqrtf(S2*(1.f/192.f)-mean[tt]*mean[tt]+1e-5f);
    }
    #pragma unroll
    for(int mt=0;mt<3;++mt){
      const f32x4 g4=*(const f32x4*)(gg+48*w+16*mt+4*lg);
      const f32x4 b4=*(const f32x4*)(bbv+48*w+16*mt+4*lg);
      #pragma unroll
      for(int tt=0;tt<4;++tt){
        u16x4 pk;
        #pragma unroll
        for(int r=0;r<4;++r) pk[r]=f2b((t[mt][tt][r]-mean[tt])*rstd[tt]*g4[r]+b4[r]);
        *(u16x4*)(sm+sa_off(16*tt+l16,(48*w+16*mt+4*lg)*2))=pk;
      }
    }
  };

  layernorm(ln1g, ln1b);
  __syncthreads();   // h visible

  // ---- QKV producer: wave w -> ct=w>>1 (ch-half of head), tok-tiles {2(w&1),+1} ----
  const int ct=w>>1, tbase=2*(w&1);
  auto c1=[&](int hh){
    f32x4 qa[2],ka[2],va[2];
    #pragma unroll
    for(int i=0;i<2;++i){ qa[i]=(f32x4){0,0,0,0}; ka[i]=(f32x4){0,0,0,0}; va[i]=(f32x4){0,0,0,0}; }
    #pragma unroll
    for(int ks=0;ks<6;++ks){
      bf16x8 hfrag[2];
      #pragma unroll
      for(int i=0;i<2;++i) hfrag[i]=*(const bf16x8*)(sm+sa_off(16*(tbase+i)+l16, ks*64+lg*16));
      const bf16x8 awq=*(const bf16x8*)(wqkvT+(      hh*32+ct*16+l16)*192+ks*32+lg*8);
      const bf16x8 awk=*(const bf16x8*)(wqkvT+(192 + hh*32+ct*16+l16)*192+ks*32+lg*8);
      const bf16x8 bwv=*(const bf16x8*)(wqkvT+(384 + hh*32+ct*16+l16)*192+ks*32+lg*8);
      #pragma unroll
      for(int i=0;i<2;++i){
        qa[i]=__builtin_amdgcn_mfma_f32_16x16x32_bf16(awq,hfrag[i],qa[i],0,0,0);  // D[qch][tok]
        ka[i]=__builtin_amdgcn_mfma_f32_16x16x32_bf16(awk,hfrag[i],ka[i],0,0,0);
        va[i]=__builtin_amdgcn_mfma_f32_16x16x32_bf16(hfrag[i],bwv,va[i],0,0,0);  // D[tok][vch]
      }
    }
    const f32x4 bq4=*(const f32x4*)(bqkv+      hh*32+ct*16+4*lg);
    const f32x4 bk4=*(const f32x4*)(bqkv+192 + hh*32+ct*16+4*lg);
    const float bv =bqkv[384 + hh*32+ct*16+l16];
    #pragma unroll
    for(int i=0;i<2;++i){
      const int tok=16*(tbase+i)+l16;
      u16x4 pq,pk,pv;
      #pragma unroll
      for(int r=0;r<4;++r){
        pq[r]=f2b(qa[i][r]+bq4[r]);
        pk[r]=f2b(ka[i][r]+bk4[r]);
        pv[r]=f2b(va[i][r]+bv);
      }
      *(u16x4*)(sm+qp_off(RQ_B,tok,32*ct+8*lg))=pq;                  // Q[tok][qch]
      *(u16x4*)(sm+qp_off(RK_B,tok,32*ct+8*lg))=pk;                  // K[tok][qch]
      *(u16x4*)(sm+vt_off(ct*16+l16,(16*(tbase+i)+4*lg)*2))=pv;      // VT[vch][tok]
    }
  };

  c1(0);
  __syncthreads();

  const float SM_C = 0.25503487f;  // log2(e)/sqrt(32), applied in f32 at exp2
  #pragma unroll 1
  for(int h=0;h<6;++h){
    // ---- S^T = K.Q (A=K rows=ktok, B=Q col=own q) ; softmax in-register ----
    {
      const int q=16*w+l16;
      const bf16x8 bqf=*(const bf16x8*)(sm+qp_off(RQ_B,q,lg*16));
      f32x4 sv[4];
      #pragma unroll
      for(int kt=0;kt<4;++kt){
        const bf16x8 akf=*(const bf16x8*)(sm+qp_off(RK_B,16*kt+l16,lg*16));
        sv[kt]=__builtin_amdgcn_mfma_f32_16x16x32_bf16(akf,bqf,(f32x4){0,0,0,0},0,0,0);
      }
      float mx=-3.0e38f;
      #pragma unroll
      for(int kt=0;kt<4;++kt){
        #pragma unroll
        for(int r=0;r<4;++r) mx=fmaxf(mx,sv[kt][r]);
      }
      mx=fmaxf(mx,__shfl_xor(mx,16)); mx=fmaxf(mx,__shfl_xor(mx,32));
      float sum=0.f;
      #pragma unroll
      for(int kt=0;kt<4;++kt){
        #pragma unroll
        for(int r=0;r<4;++r){ float e=exp2f((sv[kt][r]-mx)*SM_C); sv[kt][r]=e; sum+=e; }
      }
      sum+=__shfl_xor(sum,16); sum+=__shfl_xor(sum,32);
      const float rs=1.f/sum;
      U64 pk0,pk1,pk2,pk3;
      #pragma unroll
      for(int r=0;r<4;++r){ pk0.v[r]=f2b(sv[0][r]*rs); pk1.v[r]=f2b(sv[1][r]*rs);
                            pk2.v[r]=f2b(sv[2][r]*rs); pk3.v[r]=f2b(sv[3][r]*rs); }
      const int srcA = ((lg&1)<<5) + l16, srcB = srcA + 16;
      unsigned long long rA0=__shfl(pk0.u,srcA), rB0=__shfl(pk0.u,srcB);
      unsigned long long rA1=__shfl(pk1.u,srcA), rB1=__shfl(pk1.u,srcB);
      unsigned long long rA2=__shfl(pk2.u,srcA), rB2=__shfl(pk2.u,srcB);
      unsigned long long rA3=__shfl(pk3.u,srcA), rB3=__shfl(pk3.u,srcB);
      U128 pf0, pf1;
      pf0.q[0]=(lg<2)?rA0:rA1;  pf0.q[1]=(lg<2)?rB0:rB1;   // ktok 0..31
      pf1.q[0]=(lg<2)?rA2:rA3;  pf1.q[1]=(lg<2)?rB2:rB3;   // ktok 32..63
      // ---- PV: A=VT (rows d), B=P (col=own q) -> D[d][q]; write O[q][d] ----
      f32x4 ov[2]={(f32x4){0,0,0,0},(f32x4){0,0,0,0}};
      #pragma unroll
      for(int dt=0;dt<2;++dt){
        const bf16x8 av0=*(const bf16x8*)(sm+vt_off(16*dt+l16,lg*16));
        const bf16x8 av1=*(const bf16x8*)(sm+vt_off(16*dt+l16,64+lg*16));
        ov[dt]=__builtin_amdgcn_mfma_f32_16x16x32_bf16(av0,pf0.b,ov[dt],0,0,0);
        ov[dt]=__builtin_amdgcn_mfma_f32_16x16x32_bf16(av1,pf1.b,ov[dt],0,0,0);
      }
      #pragma unroll
      for(int dt=0;dt<2;++dt){
        u16x4 po;
        #pragma unroll
        for(int r=0;r<4;++r) po[r]=f2b(ov[dt][r]);
        *(u16x4*)(sm+qp_off(RO_B,q,32*dt+8*lg))=po;   // own q row
      }
    }
    __syncthreads();   // O visible; Q/K/VT reads done
    // ---- proj accumulate directly into t: A=Wproj rows=own outch, B=O col=tok ----
    {
      bf16x8 bo[4];
      #pragma unroll
      for(int tt=0;tt<4;++tt) bo[tt]=*(const bf16x8*)(sm+qp_off(RO_B,16*tt+l16,lg*16));
      #pragma unroll
      for(int mt=0;mt<3;++mt){
        const bf16x8 aw=*(const bf16x8*)(wprojT+(16*(3*w+mt)+l16)*192+h*32+lg*8);
        #pragma unroll
        for(int tt=0;tt<4;++tt)
          t[mt][tt]=__builtin_amdgcn_mfma_f32_16x16x32_bf16(aw,bo[tt],t[mt][tt],0,0,0);
      }
    }
    if(h<5){ c1(h+1); __syncthreads(); }
  }

  // ---- proj bias once ----
  #pragma unroll
  for(int mt=0;mt<3;++mt){
    const f32x4 bp=*(const f32x4*)(bproj+48*w+16*mt+4*lg);
    #pragma unroll
    for(int tt=0;tt<4;++tt) t[mt][tt]+=bp;
  }

  // ---- LN2 (red overlays RQ; all Q reads finished) ----
  layernorm(ln2g, ln2b);
  __syncthreads();   // h2 visible; attn buffers dead -> G area free

  // ---- MLP: 6 chunks of 128 mch; MLP2 accumulates into t ----
  #pragma unroll 1
  for(int qc=0;qc<6;++qc){
    f32x4 g[2][4];
    #pragma unroll
    for(int m=0;m<2;++m)
      #pragma unroll
      for(int tt=0;tt<4;++tt) g[m][tt]=(f32x4){0,0,0,0};
    #pragma unroll
    for(int ks=0;ks<6;++ks){
      bf16x8 bh2[4];
      #pragma unroll
      for(int tt=0;tt<4;++tt) bh2[tt]=*(const bf16x8*)(sm+sa_off(16*tt+l16,ks*64+lg*16));
      #pragma unroll
      for(int m=0;m<2;++m){
        const bf16x8 aw=*(const bf16x8*)(wmlp1T+(qc*128+16*(2*w+m)+l16)*192+ks*32+lg*8);
        #pragma unroll
        for(int tt=0;tt<4;++tt)
          g[m][tt]=__builtin_amdgcn_mfma_f32_16x16x32_bf16(aw,bh2[tt],g[m][tt],0,0,0);
      }
    }
    #pragma unroll
    for(int m=0;m<2;++m){
      const f32x4 b1=*(const f32x4*)(bmlp1+qc*128+16*(2*w+m)+4*lg);
      #pragma unroll
      for(int tt=0;tt<4;++tt){
        u16x4 pg;
        #pragma unroll
        for(int r=0;r<4;++r){
          const float xv=g[m][tt][r]+b1[r];
          pg[r]=f2b(0.5f*xv*(1.f+erff(xv*0.70710678118654752f)));
        }
        *(u16x4*)(sm+g_off(16*tt+l16,(16*(2*w+m)+4*lg)*2))=pg;  // G[tok][mch]
      }
    }
    __syncthreads();   // G visible
    #pragma unroll
    for(int ks2=0;ks2<4;++ks2){
      bf16x8 bg[4];
      #pragma unroll
      for(int tt=0;tt<4;++tt) bg[tt]=*(const bf16x8*)(sm+g_off(16*tt+l16,ks2*64+lg*16));
      #pragma unroll
      for(int mt=0;mt<3;++mt){
        const bf16x8 aw2=*(const bf16x8*)(wmlp2T+(16*(3*w+mt)+l16)*768+qc*128+ks2*32+lg*8);
        #pragma unroll
        for(int tt=0;tt<4;++tt)
          t[mt][tt]=__builtin_amdgcn_mfma_f32_16x16x32_bf16(aw2,bg[tt],t[mt][tt],0,0,0);
      }
    }
    if(qc<5) __syncthreads();  // WAR before next G write
  }

  // ---- Final: out = t + bmlp2 ----
  if(DIRECT){
    const int bb=wid>>10, wh=(wid>>5)&31, wwi=wid&31;
    const size_t imgoff=(size_t)bb*192*65536 + (size_t)(wh*8)*256 + (size_t)(wwi*8);
    #pragma unroll
    for(int mt=0;mt<3;++mt){
      const f32x4 b2=*(const f32x4*)(bmlp2+48*w+16*mt+4*lg);
      #pragma unroll
      for(int tt=0;tt<4;++tt){
        const int T=16*tt+l16, tp=(T>>3)*256+(T&7);
        #pragma unroll
        for(int r=0;r<4;++r)
          outp[imgoff+(size_t)(48*w+16*mt+4*lg+r)*65536+tp]=t[mt][tt][r]+b2[r];
      }
    }
  } else {
    float* base = outp + (size_t)wid*12288;
    #pragma unroll
    for(int mt=0;mt<3;++mt){
      const f32x4 b2=*(const f32x4*)(bmlp2+48*w+16*mt+4*lg);
      #pragma unroll
      for(int tt=0;tt<4;++tt)
        *(f32x4*)(base + (12*w+4*mt+lg)*256 + (16*tt+l16)*4)=t[mt][tt]+b2;
    }
  }
}

extern "C" void kernel_launch(void* const* d_in, const int* in_sizes, int n_in,
                              void* d_out, int out_size, void* d_ws, size_t ws_size,
                              hipStream_t stream) {
  const float* x      = (const float*)d_in[0];
  const float* w_qkv  = (const float*)d_in[1];
  const float* b_qkv  = (const float*)d_in[2];
  const float* w_proj = (const float*)d_in[3];
  const float* b_proj = (const float*)d_in[4];
  const float* ln1g   = (const float*)d_in[5];
  const float* ln1b   = (const float*)d_in[6];
  const float* ln2g   = (const float*)d_in[7];
  const float* ln2b   = (const float*)d_in[8];
  const float* w_mlp1 = (const float*)d_in[9];
  const float* b_mlp1 = (const float*)d_in[10];
  const float* w_mlp2 = (const float*)d_in[11];
  const float* b_mlp2 = (const float*)d_in[12];
  float* out = (float*)d_out;

  const size_t XW_BYTES = 4096ull*12288ull*4ull;          // 201326592
  const size_t W_PAD    = 1ull<<20;

  if (ws_size >= W_PAD + XW_BYTES){
    // Tier A: weights and xw both in d_ws
    unsigned short* wsu = (unsigned short*)d_ws;
    float* xw = (float*)((char*)d_ws + W_PAD);
    prep_weights<<<dim3(1728), dim3(256), 0, stream>>>(w_qkv, w_proj, w_mlp1, w_mlp2, wsu);
    relayout_in<<<dim3(1024), dim3(256), 0, stream>>>(x, xw);
    winblock<0><<<dim3(4096), dim3(256), 0, stream>>>(
        xw, xw, b_qkv, b_proj, ln1g, ln1b, ln2g, ln2b, b_mlp1, b_mlp2,
        wsu, wsu+110592, wsu+147456, wsu+294912);
    relayout_out<<<dim3(1024), dim3(256), 0, stream>>>(xw, out);
  } else if (ws_size >= XW_BYTES){
    // Tier B: xw fills d_ws exactly; bf16 weights parked in d_out (overwritten at the end)
    unsigned short* wsu = (unsigned short*)d_out;
    float* xw = (float*)d_ws;
    prep_weights<<<dim3(1728), dim3(256), 0, stream>>>(w_qkv, w_proj, w_mlp1, w_mlp2, wsu);
    relayout_in<<<dim3(1024), dim3(256), 0, stream>>>(x, xw);
    winblock<0><<<dim3(4096), dim3(256), 0, stream>>>(
        xw, xw, b_qkv, b_proj, ln1g, ln1b, ln2g, ln2b, b_mlp1, b_mlp2,
        wsu, wsu+110592, wsu+147456, wsu+294912);
    relayout_out<<<dim3(1024), dim3(256), 0, stream>>>(xw, out);
  } else {
    // Tier C: direct strided I/O; weights in d_ws
    unsigned short* wsu = (unsigned short*)d_ws;
    prep_weights<<<dim3(1728), dim3(256), 0, stream>>>(w_qkv, w_proj, w_mlp1, w_mlp2, wsu);
    winblock<1><<<dim3(4096), dim3(256), 0, stream>>>(
        x, out, b_qkv, b_proj, ln1g, ln1b, ln2g, ln2b, b_mlp1, b_mlp2,
        wsu, wsu+110592, wsu+147456, wsu+294912);
  }
}